// Round 1
// baseline (1511.709 us; speedup 1.0000x reference)
//
#include <hip/hip_runtime.h>
#include <hip/hip_bf16.h>
#include <cstdint>

#define B_ 4
#define S_ 2048
#define D_ 512
#define H_ 8
#define DH_ 64
#define DFF_ 2048
#define NTOK (B_*S_)
#define EPSF 1e-5f

// ---------------- flash attention (fp32), q=k=v=x, so V tile == K tile ----
__global__ __launch_bounds__(256) void attn_kernel(const float* __restrict__ x,
                                                   float* __restrict__ ctx) {
  int wg = blockIdx.x;
  int qt = wg & 31;            // S_/64 = 32 q-tiles
  int bh = wg >> 5;
  int hh = bh & 7;
  int b  = bh >> 3;
  const float* xb = x + (size_t)b * S_ * D_;
  float* cb = ctx + (size_t)b * S_ * D_;
  int q0 = qt * 64, c0 = hh * DH_;

  __shared__ float Qs[64][65];
  __shared__ float Ks[64][65];   // also serves as V
  __shared__ float Ps[64][65];

  int t = threadIdx.x;
  int ty = t >> 4, tx = t & 15;

  // load Q tile (rows q0.., cols c0..c0+63), natural layout
  #pragma unroll
  for (int i = 0; i < 4; ++i) {
    int idx = t + i * 256;
    int r = idx >> 4, ch = (idx & 15) << 2;
    float4 v = *(const float4*)&xb[(size_t)(q0 + r) * D_ + c0 + ch];
    Qs[r][ch] = v.x; Qs[r][ch + 1] = v.y; Qs[r][ch + 2] = v.z; Qs[r][ch + 3] = v.w;
  }

  float m_i[4], l_i[4], o[4][4];
  #pragma unroll
  for (int i = 0; i < 4; ++i) {
    m_i[i] = -1e30f; l_i[i] = 0.f;
    #pragma unroll
    for (int j = 0; j < 4; ++j) o[i][j] = 0.f;
  }
  const float scale = 0.125f;  // 1/sqrt(64)

  for (int kb = 0; kb < S_ / 64; ++kb) {
    __syncthreads();  // previous iteration done reading Ks/Ps; Q staged
    #pragma unroll
    for (int i = 0; i < 4; ++i) {
      int idx = t + i * 256;
      int r = idx >> 4, ch = (idx & 15) << 2;
      float4 v = *(const float4*)&xb[(size_t)(kb * 64 + r) * D_ + c0 + ch];
      Ks[r][ch] = v.x; Ks[r][ch + 1] = v.y; Ks[r][ch + 2] = v.z; Ks[r][ch + 3] = v.w;
    }
    __syncthreads();

    // S = Q K^T (64x64), 4x4 per thread
    float s[4][4];
    #pragma unroll
    for (int i = 0; i < 4; ++i)
      #pragma unroll
      for (int j = 0; j < 4; ++j) s[i][j] = 0.f;

    #pragma unroll 8
    for (int kk = 0; kk < 64; ++kk) {
      float a[4], bb[4];
      #pragma unroll
      for (int i = 0; i < 4; ++i) a[i] = Qs[ty * 4 + i][kk];
      #pragma unroll
      for (int j = 0; j < 4; ++j) bb[j] = Ks[tx * 4 + j][kk];
      #pragma unroll
      for (int i = 0; i < 4; ++i)
        #pragma unroll
        for (int j = 0; j < 4; ++j) s[i][j] += a[i] * bb[j];
    }

    // online softmax
    float p[4][4];
    #pragma unroll
    for (int i = 0; i < 4; ++i) {
      float rm = -1e30f;
      #pragma unroll
      for (int j = 0; j < 4; ++j) { s[i][j] *= scale; rm = fmaxf(rm, s[i][j]); }
      #pragma unroll
      for (int off = 1; off < 16; off <<= 1) rm = fmaxf(rm, __shfl_xor(rm, off));
      float mnew = fmaxf(m_i[i], rm);
      float esc = expf(m_i[i] - mnew);
      float rs = 0.f;
      #pragma unroll
      for (int j = 0; j < 4; ++j) { p[i][j] = expf(s[i][j] - mnew); rs += p[i][j]; }
      #pragma unroll
      for (int off = 1; off < 16; off <<= 1) rs += __shfl_xor(rs, off);
      l_i[i] = l_i[i] * esc + rs;
      m_i[i] = mnew;
      #pragma unroll
      for (int j = 0; j < 4; ++j) o[i][j] *= esc;
    }

    // stage P
    #pragma unroll
    for (int i = 0; i < 4; ++i)
      #pragma unroll
      for (int j = 0; j < 4; ++j) Ps[ty * 4 + i][tx * 4 + j] = p[i][j];
    __syncthreads();

    // O += P V   (V == Ks, natural [key][d] layout)
    #pragma unroll 8
    for (int k = 0; k < 64; ++k) {
      float pv[4], vv[4];
      #pragma unroll
      for (int i = 0; i < 4; ++i) pv[i] = Ps[ty * 4 + i][k];
      #pragma unroll
      for (int j = 0; j < 4; ++j) vv[j] = Ks[k][tx * 4 + j];
      #pragma unroll
      for (int i = 0; i < 4; ++i)
        #pragma unroll
        for (int j = 0; j < 4; ++j) o[i][j] += pv[i] * vv[j];
    }
  }

  #pragma unroll
  for (int i = 0; i < 4; ++i) {
    float inv = 1.f / l_i[i];
    #pragma unroll
    for (int j = 0; j < 4; ++j)
      cb[(size_t)(q0 + ty * 4 + i) * D_ + c0 + tx * 4 + j] = o[i][j] * inv;
  }
}

// ---------------- fp32 GEMM: C[M,Nc] = A[M,K] * W[Nc,K]^T + bias (+ReLU) ----
template <int RELU>
__global__ __launch_bounds__(256) void gemm_kernel(const float* __restrict__ A,
                                                   const float* __restrict__ W,
                                                   const float* __restrict__ bias,
                                                   float* __restrict__ C,
                                                   int M, int Nc, int K, int ntn) {
  const int BM = 128, BN = 128, BK = 16;
  __shared__ float As[BM][BK + 1];
  __shared__ float Bs[BN][BK + 1];
  int tile = blockIdx.x;
  int tn = tile % ntn, tm = tile / ntn;
  int m0 = tm * BM, n0 = tn * BN;
  int t = threadIdx.x, ty = t >> 4, tx = t & 15;

  float acc[8][8];
  #pragma unroll
  for (int i = 0; i < 8; ++i)
    #pragma unroll
    for (int j = 0; j < 8; ++j) acc[i][j] = 0.f;

  for (int k0 = 0; k0 < K; k0 += BK) {
    __syncthreads();
    {
      int r = t >> 1;
      int c = (t & 1) * 8;
      const float* ap = &A[(size_t)(m0 + r) * K + k0 + c];
      float4 a0 = *(const float4*)ap;
      float4 a1 = *(const float4*)(ap + 4);
      As[r][c + 0] = a0.x; As[r][c + 1] = a0.y; As[r][c + 2] = a0.z; As[r][c + 3] = a0.w;
      As[r][c + 4] = a1.x; As[r][c + 5] = a1.y; As[r][c + 6] = a1.z; As[r][c + 7] = a1.w;
      const float* bp = &W[(size_t)(n0 + r) * K + k0 + c];
      float4 b0 = *(const float4*)bp;
      float4 b1 = *(const float4*)(bp + 4);
      Bs[r][c + 0] = b0.x; Bs[r][c + 1] = b0.y; Bs[r][c + 2] = b0.z; Bs[r][c + 3] = b0.w;
      Bs[r][c + 4] = b1.x; Bs[r][c + 5] = b1.y; Bs[r][c + 6] = b1.z; Bs[r][c + 7] = b1.w;
    }
    __syncthreads();
    #pragma unroll
    for (int kk = 0; kk < BK; ++kk) {
      float a[8], bb[8];
      #pragma unroll
      for (int i = 0; i < 8; ++i) a[i] = As[ty * 8 + i][kk];
      #pragma unroll
      for (int j = 0; j < 8; ++j) bb[j] = Bs[tx * 8 + j][kk];
      #pragma unroll
      for (int i = 0; i < 8; ++i)
        #pragma unroll
        for (int j = 0; j < 8; ++j) acc[i][j] += a[i] * bb[j];
    }
  }

  #pragma unroll
  for (int i = 0; i < 8; ++i) {
    size_t row = (size_t)(m0 + ty * 8 + i);
    float* cp = &C[row * Nc + n0 + tx * 8];
    float4 v0, v1;
    float bv[8];
    #pragma unroll
    for (int j = 0; j < 8; ++j) {
      float v = acc[i][j] + bias[n0 + tx * 8 + j];
      if (RELU) v = fmaxf(v, 0.f);
      bv[j] = v;
    }
    v0.x = bv[0]; v0.y = bv[1]; v0.z = bv[2]; v0.w = bv[3];
    v1.x = bv[4]; v1.y = bv[5]; v1.z = bv[6]; v1.w = bv[7];
    *(float4*)cp = v0;
    *(float4*)(cp + 4) = v1;
  }
}

// ---------------- LayerNorm(in)*scale+bias + add -> out (wave per row) ----
__global__ __launch_bounds__(256) void ln_add_kernel(const float* __restrict__ in,
                                                     const float* __restrict__ scale,
                                                     const float* __restrict__ bias,
                                                     const float* __restrict__ add,
                                                     float* __restrict__ out) {
  int row = blockIdx.x * 4 + (threadIdx.x >> 6);
  int lane = threadIdx.x & 63;
  const float* rp = in + (size_t)row * D_;
  float4 v0 = *(const float4*)&rp[lane * 8];
  float4 v1 = *(const float4*)&rp[lane * 8 + 4];
  float sum = v0.x + v0.y + v0.z + v0.w + v1.x + v1.y + v1.z + v1.w;
  float ss = v0.x * v0.x + v0.y * v0.y + v0.z * v0.z + v0.w * v0.w +
             v1.x * v1.x + v1.y * v1.y + v1.z * v1.z + v1.w * v1.w;
  #pragma unroll
  for (int off = 1; off < 64; off <<= 1) {
    sum += __shfl_xor(sum, off);
    ss  += __shfl_xor(ss, off);
  }
  float mean = sum * (1.f / D_);
  float var = ss * (1.f / D_) - mean * mean;
  float rstd = rsqrtf(var + EPSF);

  const float* ap = add + (size_t)row * D_;
  float4 s0 = *(const float4*)&scale[lane * 8];
  float4 s1 = *(const float4*)&scale[lane * 8 + 4];
  float4 b0 = *(const float4*)&bias[lane * 8];
  float4 b1 = *(const float4*)&bias[lane * 8 + 4];
  float4 a0 = *(const float4*)&ap[lane * 8];
  float4 a1 = *(const float4*)&ap[lane * 8 + 4];
  float4 o0, o1;
  o0.x = (v0.x - mean) * rstd * s0.x + b0.x + a0.x;
  o0.y = (v0.y - mean) * rstd * s0.y + b0.y + a0.y;
  o0.z = (v0.z - mean) * rstd * s0.z + b0.z + a0.z;
  o0.w = (v0.w - mean) * rstd * s0.w + b0.w + a0.w;
  o1.x = (v1.x - mean) * rstd * s1.x + b1.x + a1.x;
  o1.y = (v1.y - mean) * rstd * s1.y + b1.y + a1.y;
  o1.z = (v1.z - mean) * rstd * s1.z + b1.z + a1.z;
  o1.w = (v1.w - mean) * rstd * s1.w + b1.w + a1.w;
  float* op = out + (size_t)row * D_;
  *(float4*)&op[lane * 8] = o0;
  *(float4*)&op[lane * 8 + 4] = o1;
}

extern "C" void kernel_launch(void* const* d_in, const int* in_sizes, int n_in,
                              void* d_out, int out_size, void* d_ws, size_t ws_size,
                              hipStream_t stream) {
  const float* x      = (const float*)d_in[0];
  // d_in[1]=p, d_in[2]=e : unused by the reference forward
  const float* Wo_w   = (const float*)d_in[3];
  const float* Wo_b   = (const float*)d_in[4];
  const float* ln_a_s = (const float*)d_in[5];
  const float* ln_a_b = (const float*)d_in[6];
  const float* W1_w   = (const float*)d_in[7];
  const float* W1_b   = (const float*)d_in[8];
  const float* W2_w   = (const float*)d_in[9];
  const float* W2_b   = (const float*)d_in[10];
  const float* ln_f_s = (const float*)d_in[11];
  const float* ln_f_b = (const float*)d_in[12];
  float* out = (float*)d_out;

  char* ws = (char*)d_ws;
  float* ctx  = (float*)ws;                                  // 16 MB  [B,S,D]
  float* tmp  = (float*)(ws + (size_t)16 * 1024 * 1024);     // 16 MB  [N,D]
  float* hbuf = (float*)(ws + (size_t)32 * 1024 * 1024);     // 64 MB  [N,DFF]
  // total workspace use: 96 MB

  // 1) attention -> ctx
  attn_kernel<<<B_ * H_ * (S_ / 64), 256, 0, stream>>>(x, ctx);
  // 2) attn_out(pre-LN) = ctx @ Wo^T + b -> tmp
  gemm_kernel<0><<<(NTOK / 128) * (D_ / 128), 256, 0, stream>>>(ctx, Wo_w, Wo_b, tmp,
                                                                NTOK, D_, D_, D_ / 128);
  // 3) x1 = LN(tmp) + x -> out (x1 parked in d_out)
  ln_add_kernel<<<NTOK / 4, 256, 0, stream>>>(tmp, ln_a_s, ln_a_b, x, out);
  // 4) h = relu(x1 @ W1^T + b1) -> hbuf
  gemm_kernel<1><<<(NTOK / 128) * (DFF_ / 128), 256, 0, stream>>>(out, W1_w, W1_b, hbuf,
                                                                  NTOK, DFF_, D_, DFF_ / 128);
  // 5) ffn(pre-LN) = h @ W2^T + b2 -> ctx (reuse)
  gemm_kernel<0><<<(NTOK / 128) * (D_ / 128), 256, 0, stream>>>(hbuf, W2_w, W2_b, ctx,
                                                                NTOK, D_, DFF_, D_ / 128);
  // 6) out = LN(ctx) + x1  (reads & writes d_out elementwise — safe)
  ln_add_kernel<<<NTOK / 4, 256, 0, stream>>>(ctx, ln_f_s, ln_f_b, out, out);
}

// Round 2
// 216.440 us; speedup vs baseline: 6.9844x; 6.9844x over previous
//
#include <hip/hip_runtime.h>
#include <hip/hip_bf16.h>
#include <cstdint>

#define B_ 4
#define S_ 2048
#define D_ 512
#define H_ 8
#define DH_ 64
#define DFF_ 2048
#define NTOK (B_*S_)
#define EPSF 1e-5f

using bf16x8 = __attribute__((ext_vector_type(8))) short;
using f32x4  = __attribute__((ext_vector_type(4))) float;

__device__ __forceinline__ ushort f2b(float f) {
  union { __hip_bfloat16 h; ushort u; } cv;
  cv.h = __float2bfloat16(f);
  return cv.u;
}

__device__ __forceinline__ void gload_lds16(const ushort* g, ushort* l) {
  __builtin_amdgcn_global_load_lds(
      (const __attribute__((address_space(1))) void*)g,
      (__attribute__((address_space(3))) void*)l, 16, 0, 0);
}

// ---------------- weight fp32 -> bf16 ----------------
__global__ __launch_bounds__(256) void cvt_bf16(const float* __restrict__ s,
                                                ushort* __restrict__ d, int n8) {
  int i = blockIdx.x * 256 + threadIdx.x;
  if (i >= n8) return;
  const float4* p = (const float4*)(s + (size_t)i * 8);
  float4 a = p[0], b = p[1];
  *(ushort4*)(d + (size_t)i * 8)     = make_ushort4(f2b(a.x), f2b(a.y), f2b(a.z), f2b(a.w));
  *(ushort4*)(d + (size_t)i * 8 + 4) = make_ushort4(f2b(b.x), f2b(b.y), f2b(b.z), f2b(b.w));
}

// ---------------- flash attention, bf16 MFMA ----------------
// Per WG: 64 q-rows (4 waves x 16), head dim 64, loop over 32 k-tiles of 64.
// S^T = K*Q^T  (lane owns q = l&15), then O^T = V^T * P^T.
__global__ __launch_bounds__(256) void attn_mfma(const float* __restrict__ x,
                                                 ushort* __restrict__ ctx) {
  __shared__ ushort Qs[64 * 72];
  __shared__ ushort Ks[64 * 72];
  __shared__ ushort Kt[64 * 72];
  __shared__ ushort Ps[4][16 * 72];

  int wg = blockIdx.x;
  int qt = wg & 31;
  int hh = (wg >> 5) & 7;
  int b  = wg >> 8;
  const float* xb = x + (size_t)b * S_ * D_;
  int q0 = qt * 64, c0 = hh * DH_;

  int t  = threadIdx.x;
  int l  = t & 63;
  int wv = t >> 6;
  int r0 = (t >> 4) * 4;        // staging row block
  int cc = (t & 15) * 4;        // staging col block

  // ---- stage Q (scaled by 1/sqrt(DH)=0.125; exact in bf16) ----
  {
    #pragma unroll
    for (int i = 0; i < 4; ++i) {
      float4 v = *(const float4*)&xb[(size_t)(q0 + r0 + i) * D_ + c0 + cc];
      *(ushort4*)&Qs[(r0 + i) * 72 + cc] =
        make_ushort4(f2b(v.x * 0.125f), f2b(v.y * 0.125f), f2b(v.z * 0.125f), f2b(v.w * 0.125f));
    }
  }
  __syncthreads();

  // hoist Q b-fragments (col q = l&15 within wave's strip)
  bf16x8 qf[2];
  #pragma unroll
  for (int ks = 0; ks < 2; ++ks)
    qf[ks] = *(const bf16x8*)&Qs[(wv * 16 + (l & 15)) * 72 + ks * 32 + (l >> 4) * 8];

  float m_i = -1e30f, l_i = 0.f;
  f32x4 ot[4];
  f32x4 zero = {0.f, 0.f, 0.f, 0.f};
  #pragma unroll
  for (int m = 0; m < 4; ++m) ot[m] = zero;

  for (int kb = 0; kb < S_ / 64; ++kb) {
    __syncthreads();
    // ---- stage K tile into Ks (row-major) and Kt (transposed) ----
    {
      int kr = kb * 64;
      float4 v0 = *(const float4*)&xb[(size_t)(kr + r0 + 0) * D_ + c0 + cc];
      float4 v1 = *(const float4*)&xb[(size_t)(kr + r0 + 1) * D_ + c0 + cc];
      float4 v2 = *(const float4*)&xb[(size_t)(kr + r0 + 2) * D_ + c0 + cc];
      float4 v3 = *(const float4*)&xb[(size_t)(kr + r0 + 3) * D_ + c0 + cc];
      *(ushort4*)&Ks[(r0 + 0) * 72 + cc] = make_ushort4(f2b(v0.x), f2b(v0.y), f2b(v0.z), f2b(v0.w));
      *(ushort4*)&Ks[(r0 + 1) * 72 + cc] = make_ushort4(f2b(v1.x), f2b(v1.y), f2b(v1.z), f2b(v1.w));
      *(ushort4*)&Ks[(r0 + 2) * 72 + cc] = make_ushort4(f2b(v2.x), f2b(v2.y), f2b(v2.z), f2b(v2.w));
      *(ushort4*)&Ks[(r0 + 3) * 72 + cc] = make_ushort4(f2b(v3.x), f2b(v3.y), f2b(v3.z), f2b(v3.w));
      *(ushort4*)&Kt[(cc + 0) * 72 + r0] = make_ushort4(f2b(v0.x), f2b(v1.x), f2b(v2.x), f2b(v3.x));
      *(ushort4*)&Kt[(cc + 1) * 72 + r0] = make_ushort4(f2b(v0.y), f2b(v1.y), f2b(v2.y), f2b(v3.y));
      *(ushort4*)&Kt[(cc + 2) * 72 + r0] = make_ushort4(f2b(v0.z), f2b(v1.z), f2b(v2.z), f2b(v3.z));
      *(ushort4*)&Kt[(cc + 3) * 72 + r0] = make_ushort4(f2b(v0.w), f2b(v1.w), f2b(v2.w), f2b(v3.w));
    }
    __syncthreads();

    // ---- S^T = K * Q^T : 4 m-frags (k-blocks) x 2 contraction steps ----
    f32x4 st[4];
    #pragma unroll
    for (int m = 0; m < 4; ++m) st[m] = zero;
    #pragma unroll
    for (int ks = 0; ks < 2; ++ks) {
      #pragma unroll
      for (int m = 0; m < 4; ++m) {
        bf16x8 kf = *(const bf16x8*)&Ks[(m * 16 + (l & 15)) * 72 + ks * 32 + (l >> 4) * 8];
        st[m] = __builtin_amdgcn_mfma_f32_16x16x32_bf16(kf, qf[ks], st[m], 0, 0, 0);
      }
    }

    // ---- online softmax (lane owns q = l&15; k-coverage: in-lane 16 + xor16/32) ----
    float rowm = -1e30f;
    #pragma unroll
    for (int m = 0; m < 4; ++m) {
      rowm = fmaxf(rowm, fmaxf(fmaxf(st[m][0], st[m][1]), fmaxf(st[m][2], st[m][3])));
    }
    rowm = fmaxf(rowm, __shfl_xor(rowm, 16));
    rowm = fmaxf(rowm, __shfl_xor(rowm, 32));
    float mnew = fmaxf(m_i, rowm);
    float esc = __expf(m_i - mnew);
    float rs = 0.f;
    ushort4 pw[4];
    #pragma unroll
    for (int m = 0; m < 4; ++m) {
      float p0 = __expf(st[m][0] - mnew);
      float p1 = __expf(st[m][1] - mnew);
      float p2 = __expf(st[m][2] - mnew);
      float p3 = __expf(st[m][3] - mnew);
      rs += (p0 + p1) + (p2 + p3);
      pw[m] = make_ushort4(f2b(p0), f2b(p1), f2b(p2), f2b(p3));
    }
    rs += __shfl_xor(rs, 16);
    rs += __shfl_xor(rs, 32);
    l_i = l_i * esc + rs;
    m_i = mnew;
    #pragma unroll
    for (int m = 0; m < 4; ++m) ot[m] *= esc;

    // ---- write P^T strip: lane q = l&15, k = m*16 + (l>>4)*4 + r ----
    #pragma unroll
    for (int m = 0; m < 4; ++m)
      *(ushort4*)&Ps[wv][(l & 15) * 72 + m * 16 + (l >> 4) * 4] = pw[m];

    // ---- O^T += V^T * P^T ----
    #pragma unroll
    for (int ks = 0; ks < 2; ++ks) {
      bf16x8 pf = *(const bf16x8*)&Ps[wv][(l & 15) * 72 + ks * 32 + (l >> 4) * 8];
      #pragma unroll
      for (int m = 0; m < 4; ++m) {
        bf16x8 vf = *(const bf16x8*)&Kt[(m * 16 + (l & 15)) * 72 + ks * 32 + (l >> 4) * 8];
        ot[m] = __builtin_amdgcn_mfma_f32_16x16x32_bf16(vf, pf, ot[m], 0, 0, 0);
      }
    }
  }

  // ---- normalize + write ctx (bf16), O^T: d = m*16 + (l>>4)*4 + r, q = l&15 ----
  float inv = 1.f / l_i;
  size_t qrow = (size_t)b * S_ + q0 + wv * 16 + (l & 15);
  #pragma unroll
  for (int m = 0; m < 4; ++m) {
    *(ushort4*)&ctx[qrow * D_ + c0 + m * 16 + (l >> 4) * 4] =
      make_ushort4(f2b(ot[m][0] * inv), f2b(ot[m][1] * inv),
                   f2b(ot[m][2] * inv), f2b(ot[m][3] * inv));
  }
}

// ---------------- bf16 MFMA GEMM: C[M,N] = A[M,K] * W[N,K]^T + bias ----------------
// 128x128 tile, BK=64, 4 waves (64x64 each). global_load_lds staging with
// XOR chunk swizzle c' = c ^ (row&7) applied on source address and read side.
template <int RELU, int OUTF32, int OUTB16>
__global__ __launch_bounds__(256) void gemm_bf16(const ushort* __restrict__ A,
                                                 const ushort* __restrict__ Bw,
                                                 const float* __restrict__ bias,
                                                 float* __restrict__ Cf,
                                                 ushort* __restrict__ Cb,
                                                 int M, int N, int K, int ntn) {
  __shared__ ushort As[128 * 64];
  __shared__ ushort Bs[128 * 64];
  int tile = blockIdx.x;
  int tm = tile / ntn, tn = tile % ntn;
  int m0 = tm * 128, n0 = tn * 128;
  int t = threadIdx.x, l = t & 63, wv = t >> 6;
  int wm = (wv >> 1) * 64, wn = (wv & 1) * 64;

  f32x4 zero = {0.f, 0.f, 0.f, 0.f};
  f32x4 acc[4][4];
  #pragma unroll
  for (int m = 0; m < 4; ++m)
    #pragma unroll
    for (int n = 0; n < 4; ++n) acc[m][n] = zero;

  for (int k0 = 0; k0 < K; k0 += 64) {
    __syncthreads();
    #pragma unroll
    for (int c4 = 0; c4 < 4; ++c4) {
      int jc = wv * 4 + c4;          // 1024B chunk id (16 per tile)
      int r  = jc * 8 + (l >> 3);    // row this lane feeds
      int cs = (l & 7) ^ (r & 7);    // source 16B chunk (pre-swizzled)
      gload_lds16(A  + (size_t)(m0 + r) * K + k0 + cs * 8, &As[jc * 512]);
      gload_lds16(Bw + (size_t)(n0 + r) * K + k0 + cs * 8, &Bs[jc * 512]);
    }
    __syncthreads();
    #pragma unroll
    for (int ks = 0; ks < 2; ++ks) {
      bf16x8 af[4], bf[4];
      #pragma unroll
      for (int m = 0; m < 4; ++m) {
        int r = wm + m * 16 + (l & 15);
        int c = (ks * 4 + (l >> 4)) ^ (r & 7);
        af[m] = *(const bf16x8*)&As[r * 64 + c * 8];
      }
      #pragma unroll
      for (int n = 0; n < 4; ++n) {
        int r = wn + n * 16 + (l & 15);
        int c = (ks * 4 + (l >> 4)) ^ (r & 7);
        bf[n] = *(const bf16x8*)&Bs[r * 64 + c * 8];
      }
      #pragma unroll
      for (int m = 0; m < 4; ++m)
        #pragma unroll
        for (int n = 0; n < 4; ++n)
          acc[m][n] = __builtin_amdgcn_mfma_f32_16x16x32_bf16(af[m], bf[n], acc[m][n], 0, 0, 0);
    }
  }

  float bv[4];
  #pragma unroll
  for (int n = 0; n < 4; ++n) bv[n] = bias[n0 + wn + n * 16 + (l & 15)];
  #pragma unroll
  for (int m = 0; m < 4; ++m) {
    int row = m0 + wm + m * 16 + (l >> 4) * 4;
    #pragma unroll
    for (int n = 0; n < 4; ++n) {
      int col = n0 + wn + n * 16 + (l & 15);
      #pragma unroll
      for (int r = 0; r < 4; ++r) {
        float v = acc[m][n][r] + bv[n];
        if (RELU) v = fmaxf(v, 0.f);
        if (OUTF32) Cf[(size_t)(row + r) * N + col] = v;
        if (OUTB16) Cb[(size_t)(row + r) * N + col] = f2b(v);
      }
    }
  }
}

// ---------------- LayerNorm(in)*scale+bias + add -> outf (and optional bf16 copy) ----
template <int WRITE_B16>
__global__ __launch_bounds__(256) void ln_dual_kernel(const float* __restrict__ in,
                                                      const float* __restrict__ scale,
                                                      const float* __restrict__ bias,
                                                      const float* __restrict__ add,
                                                      float* __restrict__ outf,
                                                      ushort* __restrict__ outb) {
  int row = blockIdx.x * 4 + (threadIdx.x >> 6);
  int lane = threadIdx.x & 63;
  const float* rp = in + (size_t)row * D_;
  float4 v0 = *(const float4*)&rp[lane * 8];
  float4 v1 = *(const float4*)&rp[lane * 8 + 4];
  float sum = v0.x + v0.y + v0.z + v0.w + v1.x + v1.y + v1.z + v1.w;
  float ss = v0.x * v0.x + v0.y * v0.y + v0.z * v0.z + v0.w * v0.w +
             v1.x * v1.x + v1.y * v1.y + v1.z * v1.z + v1.w * v1.w;
  #pragma unroll
  for (int off = 1; off < 64; off <<= 1) {
    sum += __shfl_xor(sum, off);
    ss  += __shfl_xor(ss, off);
  }
  float mean = sum * (1.f / D_);
  float var = ss * (1.f / D_) - mean * mean;
  float rstd = rsqrtf(var + EPSF);

  const float* ap = add + (size_t)row * D_;
  float4 s0 = *(const float4*)&scale[lane * 8];
  float4 s1 = *(const float4*)&scale[lane * 8 + 4];
  float4 b0 = *(const float4*)&bias[lane * 8];
  float4 b1 = *(const float4*)&bias[lane * 8 + 4];
  float4 a0 = *(const float4*)&ap[lane * 8];
  float4 a1 = *(const float4*)&ap[lane * 8 + 4];
  float4 o0, o1;
  o0.x = (v0.x - mean) * rstd * s0.x + b0.x + a0.x;
  o0.y = (v0.y - mean) * rstd * s0.y + b0.y + a0.y;
  o0.z = (v0.z - mean) * rstd * s0.z + b0.z + a0.z;
  o0.w = (v0.w - mean) * rstd * s0.w + b0.w + a0.w;
  o1.x = (v1.x - mean) * rstd * s1.x + b1.x + a1.x;
  o1.y = (v1.y - mean) * rstd * s1.y + b1.y + a1.y;
  o1.z = (v1.z - mean) * rstd * s1.z + b1.z + a1.z;
  o1.w = (v1.w - mean) * rstd * s1.w + b1.w + a1.w;
  float* op = outf + (size_t)row * D_;
  *(float4*)&op[lane * 8] = o0;
  *(float4*)&op[lane * 8 + 4] = o1;
  if (WRITE_B16) {
    ushort* bp = outb + (size_t)row * D_;
    *(ushort4*)&bp[lane * 8]     = make_ushort4(f2b(o0.x), f2b(o0.y), f2b(o0.z), f2b(o0.w));
    *(ushort4*)&bp[lane * 8 + 4] = make_ushort4(f2b(o1.x), f2b(o1.y), f2b(o1.z), f2b(o1.w));
  }
}

extern "C" void kernel_launch(void* const* d_in, const int* in_sizes, int n_in,
                              void* d_out, int out_size, void* d_ws, size_t ws_size,
                              hipStream_t stream) {
  const float* x      = (const float*)d_in[0];
  const float* Wo_w   = (const float*)d_in[3];
  const float* Wo_b   = (const float*)d_in[4];
  const float* ln_a_s = (const float*)d_in[5];
  const float* ln_a_b = (const float*)d_in[6];
  const float* W1_w   = (const float*)d_in[7];
  const float* W1_b   = (const float*)d_in[8];
  const float* W2_w   = (const float*)d_in[9];
  const float* W2_b   = (const float*)d_in[10];
  const float* ln_f_s = (const float*)d_in[11];
  const float* ln_f_b = (const float*)d_in[12];
  float* out = (float*)d_out;

  char* ws = (char*)d_ws;
  const size_t MB = 1024 * 1024;
  ushort* wob  = (ushort*)(ws);                 // 0.5 MB
  ushort* w1b  = (ushort*)(ws + 1 * MB);        // 2 MB
  ushort* w2b  = (ushort*)(ws + 3 * MB);        // 2 MB
  ushort* ctxb = (ushort*)(ws + 5 * MB);        // 8 MB
  ushort* x1b  = (ushort*)(ws + 13 * MB);       // 8 MB
  float*  tmp  = (float*)(ws + 21 * MB);        // 16 MB
  ushort* hb   = (ushort*)(ws + 37 * MB);       // 32 MB  (ends at 69 MB)

  // weights -> bf16
  cvt_bf16<<<128, 256, 0, stream>>>(Wo_w, wob, (D_ * D_) / 8);
  cvt_bf16<<<512, 256, 0, stream>>>(W1_w, w1b, (DFF_ * D_) / 8);
  cvt_bf16<<<512, 256, 0, stream>>>(W2_w, w2b, (D_ * DFF_) / 8);

  // attention -> ctx (bf16)
  attn_mfma<<<B_ * H_ * (S_ / 64), 256, 0, stream>>>(x, ctxb);

  // attn_out(pre-LN) = ctx @ Wo^T + b -> tmp (f32)
  gemm_bf16<0, 1, 0><<<(NTOK / 128) * (D_ / 128), 256, 0, stream>>>(
      ctxb, wob, Wo_b, tmp, nullptr, NTOK, D_, D_, D_ / 128);

  // x1 = LN(tmp) + x -> d_out (f32) and x1b (bf16)
  ln_dual_kernel<1><<<NTOK / 4, 256, 0, stream>>>(tmp, ln_a_s, ln_a_b, x, out, x1b);

  // h = relu(x1 @ W1^T + b1) -> hb (bf16)
  gemm_bf16<1, 0, 1><<<(NTOK / 128) * (DFF_ / 128), 256, 0, stream>>>(
      x1b, w1b, W1_b, nullptr, hb, NTOK, DFF_, D_, DFF_ / 128);

  // ffn(pre-LN) = h @ W2^T + b2 -> tmp (f32)
  gemm_bf16<0, 1, 0><<<(NTOK / 128) * (D_ / 128), 256, 0, stream>>>(
      hb, w2b, W2_b, tmp, nullptr, NTOK, D_, DFF_, D_ / 128);

  // out = LN(tmp) + x1
  ln_dual_kernel<0><<<NTOK / 4, 256, 0, stream>>>(tmp, ln_f_s, ln_f_b, out, out, nullptr);
}

// Round 3
// 185.743 us; speedup vs baseline: 8.1387x; 1.1653x over previous
//
#include <hip/hip_runtime.h>
#include <hip/hip_bf16.h>
#include <cstdint>

#define B_ 4
#define S_ 2048
#define D_ 512
#define H_ 8
#define DH_ 64
#define DFF_ 2048
#define NTOK (B_*S_)
#define EPSF 1e-5f

using bf16x8 = __attribute__((ext_vector_type(8))) short;
using u16x8  = __attribute__((ext_vector_type(8))) unsigned short;
using f32x4  = __attribute__((ext_vector_type(4))) float;

__device__ __forceinline__ ushort f2b(float f) {
  union { __hip_bfloat16 h; ushort u; } cv;
  cv.h = __float2bfloat16(f);
  return cv.u;
}

__device__ __forceinline__ void gload_lds16(const ushort* g, ushort* l) {
  __builtin_amdgcn_global_load_lds(
      (const __attribute__((address_space(1))) void*)g,
      (__attribute__((address_space(3))) void*)l, 16, 0, 0);
}

// ---------------- x f32 -> xb bf16 [B,S,D] and xT bf16 [B,D,S] ----------------
__global__ __launch_bounds__(256) void xcvt_kernel(const float* __restrict__ x,
                                                   ushort* __restrict__ xb,
                                                   ushort* __restrict__ xT) {
  __shared__ ushort T[64 * 72];
  int wg = blockIdx.x;
  int dt = wg & 7;            // D/64 = 8
  int st = (wg >> 3) & 31;    // S/64 = 32
  int b  = wg >> 8;
  int s0 = st * 64, d0 = dt * 64;
  int t = threadIdx.x;
  int r0 = (t >> 4) * 4, cc = (t & 15) * 4;

  ushort4 w[4];
  #pragma unroll
  for (int i = 0; i < 4; ++i) {
    float4 v = *(const float4*)&x[((size_t)b * S_ + s0 + r0 + i) * D_ + d0 + cc];
    w[i] = make_ushort4(f2b(v.x), f2b(v.y), f2b(v.z), f2b(v.w));
    *(ushort4*)&xb[((size_t)b * S_ + s0 + r0 + i) * D_ + d0 + cc] = w[i];
  }
  *(ushort4*)&T[(cc + 0) * 72 + r0] = make_ushort4(w[0].x, w[1].x, w[2].x, w[3].x);
  *(ushort4*)&T[(cc + 1) * 72 + r0] = make_ushort4(w[0].y, w[1].y, w[2].y, w[3].y);
  *(ushort4*)&T[(cc + 2) * 72 + r0] = make_ushort4(w[0].z, w[1].z, w[2].z, w[3].z);
  *(ushort4*)&T[(cc + 3) * 72 + r0] = make_ushort4(w[0].w, w[1].w, w[2].w, w[3].w);
  __syncthreads();
  int dd = t >> 2, sc = (t & 3) * 16;
  ushort* dst = &xT[((size_t)b * D_ + d0 + dd) * S_ + s0 + sc];
  *(u16x8*)dst       = *(const u16x8*)&T[dd * 72 + sc];
  *(u16x8*)(dst + 8) = *(const u16x8*)&T[dd * 72 + sc + 8];
}

// ---------------- all weights f32 -> bf16 in one launch ----------------
__global__ __launch_bounds__(256) void wcvt_kernel(const float* __restrict__ a, ushort* __restrict__ da, int na8,
                                                   const float* __restrict__ b, ushort* __restrict__ db, int nb8,
                                                   const float* __restrict__ c, ushort* __restrict__ dc, int nc8) {
  int i = blockIdx.x * 256 + threadIdx.x;
  const float* s; ushort* d; int j = i;
  if (j < na8) { s = a; d = da; }
  else {
    j -= na8;
    if (j < nb8) { s = b; d = db; }
    else { j -= nb8; if (j >= nc8) return; s = c; d = dc; }
  }
  const float4* p = (const float4*)(s + (size_t)j * 8);
  float4 v0 = p[0], v1 = p[1];
  *(ushort4*)(d + (size_t)j * 8)     = make_ushort4(f2b(v0.x), f2b(v0.y), f2b(v0.z), f2b(v0.w));
  *(ushort4*)(d + (size_t)j * 8 + 4) = make_ushort4(f2b(v1.x), f2b(v1.y), f2b(v1.z), f2b(v1.w));
}

// ---------------- flash attention, bf16 MFMA, DMA staging ----------------
// Per WG: 64 q-rows (4 waves x 16), DH=64, 32 k-tiles of 64 keys.
// S^T = K*Q^T (lane owns q = l&15), then O^T = V^T * P^T (V^T tile = Kt from xT).
__global__ __launch_bounds__(256) void attn_mfma(const ushort* __restrict__ xb,
                                                 const ushort* __restrict__ xT,
                                                 ushort* __restrict__ ctx) {
  __shared__ ushort Ks[64 * 64];
  __shared__ ushort Kt[64 * 64];
  __shared__ ushort Ps[4][16 * 72];   // first reused as Q staging (8192B of 9216B)

  int wg = blockIdx.x;
  int qt = wg & 31;
  int hh = (wg >> 5) & 7;
  int b  = wg >> 8;
  int q0 = qt * 64, c0 = hh * DH_;
  int t = threadIdx.x, l = t & 63, wv = t >> 6;

  const ushort* xbb = xb + (size_t)b * S_ * D_;
  const ushort* xTb = xT + (size_t)b * D_ * S_;

  int rr = l >> 3;            // row within 8-row chunk
  int sbk = (l & 7) ^ rr;     // XOR-swizzled source 16B-block

  // ---- stage Q into Ps region (linear dest, pre-swizzled source) ----
  ushort* Qlds = (ushort*)Ps;
  #pragma unroll
  for (int c = 0; c < 2; ++c) {
    int j = wv * 2 + c;
    gload_lds16(xbb + (size_t)(q0 + j * 8 + rr) * D_ + c0 + sbk * 8, Qlds + j * 512);
  }
  __syncthreads();
  bf16x8 qf[2];
  {
    int row = wv * 16 + (l & 15);
    #pragma unroll
    for (int ks = 0; ks < 2; ++ks)
      qf[ks] = *(const bf16x8*)&Qlds[row * 64 + (((ks * 4 + (l >> 4)) ^ (row & 7)) * 8)];
  }

  float m_i = -1e30f, l_i = 0.f;
  f32x4 zero = {0.f, 0.f, 0.f, 0.f};
  f32x4 ot[4];
  #pragma unroll
  for (int m = 0; m < 4; ++m) ot[m] = zero;

  for (int kb = 0; kb < S_ / 64; ++kb) {
    int kr = kb * 64;
    __syncthreads();   // all waves done reading Ks/Kt (and qf on iter 0)
    #pragma unroll
    for (int c = 0; c < 2; ++c) {
      int j = wv * 2 + c;
      gload_lds16(xbb + (size_t)(kr + j * 8 + rr) * D_ + c0 + sbk * 8, &Ks[j * 512]);
      gload_lds16(xTb + (size_t)(c0 + j * 8 + rr) * S_ + kr + sbk * 8, &Kt[j * 512]);
    }
    __syncthreads();

    // ---- S^T = K * Q^T ----
    f32x4 st[4];
    #pragma unroll
    for (int m = 0; m < 4; ++m) st[m] = zero;
    __builtin_amdgcn_s_setprio(1);
    #pragma unroll
    for (int ks = 0; ks < 2; ++ks) {
      #pragma unroll
      for (int m = 0; m < 4; ++m) {
        int row = m * 16 + (l & 15);
        bf16x8 kf = *(const bf16x8*)&Ks[row * 64 + (((ks * 4 + (l >> 4)) ^ (row & 7)) * 8)];
        st[m] = __builtin_amdgcn_mfma_f32_16x16x32_bf16(kf, qf[ks], st[m], 0, 0, 0);
      }
    }
    __builtin_amdgcn_s_setprio(0);

    // ---- online softmax; scale 0.125 folded into exp FMA ----
    float rowm = -1e30f;
    #pragma unroll
    for (int m = 0; m < 4; ++m)
      rowm = fmaxf(rowm, fmaxf(fmaxf(st[m][0], st[m][1]), fmaxf(st[m][2], st[m][3])));
    rowm = fmaxf(rowm, __shfl_xor(rowm, 16));
    rowm = fmaxf(rowm, __shfl_xor(rowm, 32));
    float mnew = fmaxf(m_i, rowm);
    float ms = mnew * 0.125f;
    float esc = __expf(m_i * 0.125f - ms);
    float rs = 0.f;
    ushort4 pw[4];
    #pragma unroll
    for (int m = 0; m < 4; ++m) {
      float p0 = __expf(st[m][0] * 0.125f - ms);
      float p1 = __expf(st[m][1] * 0.125f - ms);
      float p2 = __expf(st[m][2] * 0.125f - ms);
      float p3 = __expf(st[m][3] * 0.125f - ms);
      rs += (p0 + p1) + (p2 + p3);
      pw[m] = make_ushort4(f2b(p0), f2b(p1), f2b(p2), f2b(p3));
    }
    rs += __shfl_xor(rs, 16);
    rs += __shfl_xor(rs, 32);
    l_i = l_i * esc + rs;
    m_i = mnew;
    #pragma unroll
    for (int m = 0; m < 4; ++m) ot[m] *= esc;

    // ---- P^T strip: lane q = l&15, key = m*16 + (l>>4)*4 + r ----
    #pragma unroll
    for (int m = 0; m < 4; ++m)
      *(ushort4*)&Ps[wv][(l & 15) * 72 + m * 16 + (l >> 4) * 4] = pw[m];

    // ---- O^T += V^T * P^T ----
    __builtin_amdgcn_s_setprio(1);
    #pragma unroll
    for (int ks = 0; ks < 2; ++ks) {
      bf16x8 pf = *(const bf16x8*)&Ps[wv][(l & 15) * 72 + ks * 32 + (l >> 4) * 8];
      #pragma unroll
      for (int m = 0; m < 4; ++m) {
        int row = m * 16 + (l & 15);
        bf16x8 vf = *(const bf16x8*)&Kt[row * 64 + (((ks * 4 + (l >> 4)) ^ (row & 7)) * 8)];
        ot[m] = __builtin_amdgcn_mfma_f32_16x16x32_bf16(vf, pf, ot[m], 0, 0, 0);
      }
    }
    __builtin_amdgcn_s_setprio(0);
  }

  // ---- normalize + write ctx (bf16): d = m*16 + (l>>4)*4 + r, q = l&15 ----
  float inv = 1.f / l_i;
  size_t qrow = (size_t)b * S_ + q0 + wv * 16 + (l & 15);
  #pragma unroll
  for (int m = 0; m < 4; ++m) {
    *(ushort4*)&ctx[qrow * D_ + c0 + m * 16 + (l >> 4) * 4] =
      make_ushort4(f2b(ot[m][0] * inv), f2b(ot[m][1] * inv),
                   f2b(ot[m][2] * inv), f2b(ot[m][3] * inv));
  }
}

// ---------------- bf16 MFMA GEMM: C[M,N] = A[M,K] * W[N,K]^T + bias ----------------
template <int RELU, int OUTF32, int OUTB16>
__global__ __launch_bounds__(256) void gemm_bf16(const ushort* __restrict__ A,
                                                 const ushort* __restrict__ Bw,
                                                 const float* __restrict__ bias,
                                                 float* __restrict__ Cf,
                                                 ushort* __restrict__ Cb,
                                                 int M, int N, int K, int ntn) {
  __shared__ ushort As[128 * 64];
  __shared__ ushort Bs[128 * 64];
  int nwg = gridDim.x;
  int tile = blockIdx.x;
  int cpx = nwg >> 3;                         // grids are %8 == 0
  tile = (tile & 7) * cpx + (tile >> 3);      // XCD-contiguous remap
  int tm = tile / ntn, tn = tile % ntn;
  int m0 = tm * 128, n0 = tn * 128;
  int t = threadIdx.x, l = t & 63, wv = t >> 6;
  int wm = (wv >> 1) * 64, wn = (wv & 1) * 64;

  f32x4 zero = {0.f, 0.f, 0.f, 0.f};
  f32x4 acc[4][4];
  #pragma unroll
  for (int m = 0; m < 4; ++m)
    #pragma unroll
    for (int n = 0; n < 4; ++n) acc[m][n] = zero;

  for (int k0 = 0; k0 < K; k0 += 64) {
    __syncthreads();
    #pragma unroll
    for (int c4 = 0; c4 < 4; ++c4) {
      int jc = wv * 4 + c4;
      int r  = jc * 8 + (l >> 3);
      int cs = (l & 7) ^ (r & 7);
      gload_lds16(A  + (size_t)(m0 + r) * K + k0 + cs * 8, &As[jc * 512]);
      gload_lds16(Bw + (size_t)(n0 + r) * K + k0 + cs * 8, &Bs[jc * 512]);
    }
    __syncthreads();
    #pragma unroll
    for (int ks = 0; ks < 2; ++ks) {
      bf16x8 af[4], bf[4];
      #pragma unroll
      for (int m = 0; m < 4; ++m) {
        int r = wm + m * 16 + (l & 15);
        int c = (ks * 4 + (l >> 4)) ^ (r & 7);
        af[m] = *(const bf16x8*)&As[r * 64 + c * 8];
      }
      #pragma unroll
      for (int n = 0; n < 4; ++n) {
        int r = wn + n * 16 + (l & 15);
        int c = (ks * 4 + (l >> 4)) ^ (r & 7);
        bf[n] = *(const bf16x8*)&Bs[r * 64 + c * 8];
      }
      #pragma unroll
      for (int m = 0; m < 4; ++m)
        #pragma unroll
        for (int n = 0; n < 4; ++n)
          acc[m][n] = __builtin_amdgcn_mfma_f32_16x16x32_bf16(af[m], bf[n], acc[m][n], 0, 0, 0);
    }
  }

  float bv[4];
  #pragma unroll
  for (int n = 0; n < 4; ++n) bv[n] = bias[n0 + wn + n * 16 + (l & 15)];
  #pragma unroll
  for (int m = 0; m < 4; ++m) {
    int row = m0 + wm + m * 16 + (l >> 4) * 4;
    #pragma unroll
    for (int n = 0; n < 4; ++n) {
      int col = n0 + wn + n * 16 + (l & 15);
      #pragma unroll
      for (int r = 0; r < 4; ++r) {
        float v = acc[m][n][r] + bv[n];
        if (RELU) v = fmaxf(v, 0.f);
        if (OUTF32) Cf[(size_t)(row + r) * N + col] = v;
        if (OUTB16) Cb[(size_t)(row + r) * N + col] = f2b(v);
      }
    }
  }
}

// ---------------- LayerNorm(in)*scale+bias + add -> outf (and optional bf16 copy) ----
template <int WRITE_B16>
__global__ __launch_bounds__(256) void ln_dual_kernel(const float* __restrict__ in,
                                                      const float* __restrict__ scale,
                                                      const float* __restrict__ bias,
                                                      const float* __restrict__ add,
                                                      float* __restrict__ outf,
                                                      ushort* __restrict__ outb) {
  int row = blockIdx.x * 4 + (threadIdx.x >> 6);
  int lane = threadIdx.x & 63;
  const float* rp = in + (size_t)row * D_;
  float4 v0 = *(const float4*)&rp[lane * 8];
  float4 v1 = *(const float4*)&rp[lane * 8 + 4];
  float sum = v0.x + v0.y + v0.z + v0.w + v1.x + v1.y + v1.z + v1.w;
  float ss = v0.x * v0.x + v0.y * v0.y + v0.z * v0.z + v0.w * v0.w +
             v1.x * v1.x + v1.y * v1.y + v1.z * v1.z + v1.w * v1.w;
  #pragma unroll
  for (int off = 1; off < 64; off <<= 1) {
    sum += __shfl_xor(sum, off);
    ss  += __shfl_xor(ss, off);
  }
  float mean = sum * (1.f / D_);
  float var = ss * (1.f / D_) - mean * mean;
  float rstd = rsqrtf(var + EPSF);

  const float* ap = add + (size_t)row * D_;
  float4 s0 = *(const float4*)&scale[lane * 8];
  float4 s1 = *(const float4*)&scale[lane * 8 + 4];
  float4 b0 = *(const float4*)&bias[lane * 8];
  float4 b1 = *(const float4*)&bias[lane * 8 + 4];
  float4 a0 = *(const float4*)&ap[lane * 8];
  float4 a1 = *(const float4*)&ap[lane * 8 + 4];
  float4 o0, o1;
  o0.x = (v0.x - mean) * rstd * s0.x + b0.x + a0.x;
  o0.y = (v0.y - mean) * rstd * s0.y + b0.y + a0.y;
  o0.z = (v0.z - mean) * rstd * s0.z + b0.z + a0.z;
  o0.w = (v0.w - mean) * rstd * s0.w + b0.w + a0.w;
  o1.x = (v1.x - mean) * rstd * s1.x + b1.x + a1.x;
  o1.y = (v1.y - mean) * rstd * s1.y + b1.y + a1.y;
  o1.z = (v1.z - mean) * rstd * s1.z + b1.z + a1.z;
  o1.w = (v1.w - mean) * rstd * s1.w + b1.w + a1.w;
  float* op = outf + (size_t)row * D_;
  *(float4*)&op[lane * 8] = o0;
  *(float4*)&op[lane * 8 + 4] = o1;
  if (WRITE_B16) {
    ushort* bp = outb + (size_t)row * D_;
    *(ushort4*)&bp[lane * 8]     = make_ushort4(f2b(o0.x), f2b(o0.y), f2b(o0.z), f2b(o0.w));
    *(ushort4*)&bp[lane * 8 + 4] = make_ushort4(f2b(o1.x), f2b(o1.y), f2b(o1.z), f2b(o1.w));
  }
}

extern "C" void kernel_launch(void* const* d_in, const int* in_sizes, int n_in,
                              void* d_out, int out_size, void* d_ws, size_t ws_size,
                              hipStream_t stream) {
  const float* x      = (const float*)d_in[0];
  const float* Wo_w   = (const float*)d_in[3];
  const float* Wo_b   = (const float*)d_in[4];
  const float* ln_a_s = (const float*)d_in[5];
  const float* ln_a_b = (const float*)d_in[6];
  const float* W1_w   = (const float*)d_in[7];
  const float* W1_b   = (const float*)d_in[8];
  const float* W2_w   = (const float*)d_in[9];
  const float* W2_b   = (const float*)d_in[10];
  const float* ln_f_s = (const float*)d_in[11];
  const float* ln_f_b = (const float*)d_in[12];
  float* out = (float*)d_out;

  char* ws = (char*)d_ws;
  const size_t MB = 1024 * 1024;
  ushort* xbb  = (ushort*)(ws);                 // 8 MB   [B,S,D] bf16
  ushort* xTb  = (ushort*)(ws + 8 * MB);        // 8 MB   [B,D,S] bf16
  ushort* wob  = (ushort*)(ws + 16 * MB);       // 0.5 MB
  ushort* w1b  = (ushort*)(ws + 17 * MB);       // 2 MB
  ushort* w2b  = (ushort*)(ws + 19 * MB);       // 2 MB
  ushort* ctxb = (ushort*)(ws + 21 * MB);       // 8 MB
  ushort* x1b  = (ushort*)(ws + 29 * MB);       // 8 MB
  float*  tmp  = (float*)(ws + 37 * MB);        // 16 MB
  ushort* hb   = (ushort*)(ws + 53 * MB);       // 32 MB  (ends at 85 MB)

  // x -> bf16 (straight + transposed)
  xcvt_kernel<<<B_ * (S_ / 64) * (D_ / 64), 256, 0, stream>>>(x, xbb, xTb);
  // weights -> bf16 (single launch)
  wcvt_kernel<<<1152, 256, 0, stream>>>(Wo_w, wob, (D_ * D_) / 8,
                                        W1_w, w1b, (DFF_ * D_) / 8,
                                        W2_w, w2b, (D_ * DFF_) / 8);

  // attention -> ctx (bf16)
  attn_mfma<<<B_ * H_ * (S_ / 64), 256, 0, stream>>>(xbb, xTb, ctxb);

  // attn_out(pre-LN) = ctx @ Wo^T + b -> tmp (f32)
  gemm_bf16<0, 1, 0><<<(NTOK / 128) * (D_ / 128), 256, 0, stream>>>(
      ctxb, wob, Wo_b, tmp, nullptr, NTOK, D_, D_, D_ / 128);

  // x1 = LN(tmp) + x -> d_out (f32) and x1b (bf16)
  ln_dual_kernel<1><<<NTOK / 4, 256, 0, stream>>>(tmp, ln_a_s, ln_a_b, x, out, x1b);

  // h = relu(x1 @ W1^T + b1) -> hb (bf16)
  gemm_bf16<1, 0, 1><<<(NTOK / 128) * (DFF_ / 128), 256, 0, stream>>>(
      x1b, w1b, W1_b, nullptr, hb, NTOK, DFF_, D_, DFF_ / 128);

  // ffn(pre-LN) = h @ W2^T + b2 -> tmp (f32)
  gemm_bf16<0, 1, 0><<<(NTOK / 128) * (D_ / 128), 256, 0, stream>>>(
      hb, w2b, W2_b, tmp, nullptr, NTOK, D_, DFF_, D_ / 128);

  // out = LN(tmp) + x1
  ln_dual_kernel<0><<<NTOK / 4, 256, 0, stream>>>(tmp, ln_f_s, ln_f_b, out, out, nullptr);
}